// Round 2
// baseline (885.251 us; speedup 1.0000x reference)
//
#include <hip/hip_runtime.h>
#include <hip/hip_bf16.h>
#include <stdint.h>

typedef __hip_bfloat16 bf16;
typedef __attribute__((ext_vector_type(8))) short bf16x8;   // 8 bf16 = 4 VGPR
typedef __attribute__((ext_vector_type(4))) float f32x4;

#define B_DIM 4096
#define H_DIM 2048
#define CH1_DIM 256
#define CH2_DIM 128
#define NMEM_DIM 4096

__device__ __forceinline__ float bf2f(bf16 v) { return __bfloat162float(v); }
__device__ __forceinline__ bf16 f2bf(float v) { return __float2bfloat16(v); }

__device__ __forceinline__ float gelu_f(float x) {
  float u = 0.7978845608028654f * (x + 0.044715f * x * x * x);
  float t = 1.0f - 2.0f / (__expf(2.0f * u) + 1.0f);
  return 0.5f * x * (1.0f + t);
}
__device__ __forceinline__ float sigmoid_f(float x) {
  return 1.0f / (1.0f + __expf(-x));
}

__device__ __forceinline__ void async16(const void* g, void* l) {
  __builtin_amdgcn_global_load_lds(
      (const __attribute__((address_space(1))) char*)(uintptr_t)g,
      (__attribute__((address_space(3))) char*)(uintptr_t)l, 16, 0, 0);
}

// low 32 bits of a flat LDS pointer == LDS byte offset (same truncation
// async16 relies on, hardware-verified by passing rounds)
__device__ __forceinline__ uint32_t laddr(const void* p) {
  return (uint32_t)(uintptr_t)p;
}

#define SBAR0() __builtin_amdgcn_sched_barrier(0)
// raw barrier: no memory clobber -> compiler must NOT insert vmcnt(0) drains
__device__ __forceinline__ void hbar() {
  SBAR0();
  __builtin_amdgcn_s_barrier();
  SBAR0();
}
__device__ __forceinline__ void wait_lgkm0() {
  asm volatile("s_waitcnt lgkmcnt(0)");
  SBAR0();  // rule 18: stop MFMA hoisting past the wait
}

// ---------------------------------------------------------------------------
// dtype probe: flag=1 -> inputs are float32, flag=0 -> bfloat16.
// ---------------------------------------------------------------------------
__global__ void flag_init(int* flag) { *flag = 0; }

__global__ void probe_dtype(const void* x, int* flag) {
  const unsigned short* u = (const unsigned short*)x;
  int i0 = blockIdx.x * 256 + threadIdx.x;
  bool big = false;
#pragma unroll
  for (int k = 0; k < 16; ++k) {
    unsigned short h = u[(size_t)(i0 * 16 + k) * 2];  // even bf16-view index
    unsigned int e = (h >> 7) & 0xFF;
    if (e >= 0x9A) big = true;  // |v| >= 2^27 or inf/nan -> f32 mantissa noise
  }
  if (big) atomicOr(flag, 1);
}

__global__ void ingest(const void* src, bf16* dst, int n, const int* flag) {
  int i = blockIdx.x * 256 + threadIdx.x;
  if (i >= n) return;
  if (*flag) dst[i] = f2bf(((const float*)src)[i]);
  else       dst[i] = ((const bf16*)src)[i];
}

struct SmallJobs { const void* src[9]; bf16* dst[9]; int n[9]; };
__global__ void ingest_small(SmallJobs jobs, const int* flag) {
  int b = blockIdx.x;
  const void* src = jobs.src[b];
  bf16* dst = jobs.dst[b];
  int n = jobs.n[b];
  bool isf = *flag != 0;
  for (int i = threadIdx.x; i < n; i += 256)
    dst[i] = isf ? f2bf(((const float*)src)[i]) : ((const bf16*)src)[i];
}

// ---------------------------------------------------------------------------
// 128^2-tile GEMM (Round-2 verified, kept for N=2048 shapes: mq, rw2).
// ---------------------------------------------------------------------------
template <int BT, int ACT, int STAT>
__global__ __launch_bounds__(256, 2) void gemm_bt(
    const bf16* __restrict__ A, const bf16* __restrict__ Bt,
    const bf16* __restrict__ bias, bf16* __restrict__ C,
    float* __restrict__ qsum, int M, int N, int K,
    const int* __restrict__ gate) {
  if (gate && *gate == 0) return;
  constexpr int CH = BT / 32;
  constexpr int FR = BT / 32;
  __shared__ __align__(16) bf16 As[BT * 64];
  __shared__ __align__(16) bf16 Bs[BT * 64];

  const int t = threadIdx.x;
  const int lane = t & 63;
  const int wave = t >> 6;
  const int m0 = blockIdx.y * BT;
  const int n0 = blockIdx.x * BT;

  const bf16* gA[CH];
  const bf16* gB[CH];
  int lOff[CH];
#pragma unroll
  for (int p = 0; p < CH; ++p) {
    int c = p * 256 + t;
    int r = c >> 3;
    int g = (c & 7) ^ (r & 7);  // logical k-group stored at this slot
    gA[p] = A + (size_t)(m0 + r) * K + g * 8;
    gB[p] = Bt + (size_t)(n0 + r) * K + g * 8;
    lOff[p] = c * 16;
  }

  f32x4 acc[FR][FR];
#pragma unroll
  for (int i = 0; i < FR; ++i)
#pragma unroll
    for (int j = 0; j < FR; ++j) acc[i][j] = (f32x4){0.f, 0.f, 0.f, 0.f};

  const int wrow = (wave >> 1) * (FR * 16);
  const int wcol = (wave & 1) * (FR * 16);
  const int l15 = lane & 15;
  const int quad = lane >> 4;

  for (int kt = 0; kt < K; kt += 64) {
#pragma unroll
    for (int p = 0; p < CH; ++p) {
      async16(gA[p], (char*)As + lOff[p]);
      async16(gB[p], (char*)Bs + lOff[p]);
      gA[p] += 64;
      gB[p] += 64;
    }
    asm volatile("s_waitcnt vmcnt(0)" ::: "memory");
    __syncthreads();
#pragma unroll
    for (int ks = 0; ks < 2; ++ks) {
      bf16x8 af[FR], bfv[FR];
#pragma unroll
      for (int i = 0; i < FR; ++i) {
        int ra = wrow + i * 16 + l15;
        int g = ks * 4 + quad;
        af[i] = *(const bf16x8*)(As + ra * 64 + ((g ^ (ra & 7)) * 8));
        int rb = wcol + i * 16 + l15;
        bfv[i] = *(const bf16x8*)(Bs + rb * 64 + ((g ^ (rb & 7)) * 8));
      }
#pragma unroll
      for (int i = 0; i < FR; ++i)
#pragma unroll
        for (int j = 0; j < FR; ++j)
          acc[i][j] = __builtin_amdgcn_mfma_f32_16x16x32_bf16(af[i], bfv[j],
                                                              acc[i][j], 0, 0, 0);
    }
    __syncthreads();
  }

  if constexpr (STAT == 0) {
#pragma unroll
    for (int j = 0; j < FR; ++j) {
      int col = n0 + wcol + j * 16 + l15;
      float bv = bf2f(bias[col]);
#pragma unroll
      for (int i = 0; i < FR; ++i) {
#pragma unroll
        for (int r = 0; r < 4; ++r) {
          int row = m0 + wrow + i * 16 + quad * 4 + r;
          float v = acc[i][j][r] + bv;
          if (ACT == 1) v = gelu_f(v);
          C[(size_t)row * N + col] = f2bf(v);
        }
      }
    }
  } else {
    float bv[FR];
#pragma unroll
    for (int j = 0; j < FR; ++j) bv[j] = bf2f(bias[n0 + wcol + j * 16 + l15]);
#pragma unroll
    for (int i = 0; i < FR; ++i) {
#pragma unroll
      for (int r = 0; r < 4; ++r) {
        int row = m0 + wrow + i * 16 + quad * 4 + r;
        float ss = 0.f;
#pragma unroll
        for (int j = 0; j < FR; ++j) {
          int col = n0 + wcol + j * 16 + l15;
          float v = acc[i][j][r] + bv[j];
          if (ACT == 1) v = gelu_f(v);
          C[(size_t)row * N + col] = f2bf(v);
          ss += v * v;
        }
#pragma unroll
        for (int m = 1; m < 16; m <<= 1) ss += __shfl_xor(ss, m, 64);
        if (l15 == 0) atomicAdd(qsum + row, ss);
      }
    }
  }
}

// ---------------------------------------------------------------------------
// 256^2-tile 8-phase GEMM core, v2 (post-mortem fixes):
//  - inline-asm ds_read_b128 from 4 hoisted swizzled bases + imm offsets
//    (swizzle term (g^(ra&7)) is lane-constant: ra&7 == l15&7) -> no per-phase
//    address VALU, no compiler-visible LDS aliasing
//  - raw s_barrier + bare waitcnt asm (NO memory clobbers) so the compiler
//    cannot insert vmcnt(0) drains; counted vmcnt(4) at phases 4/8 only
//  - sched_barrier(0) fences pin phase boundaries + rule-18 lgkmcnt guard
// Stage slotting (unchanged from verified r0 schedule):
//   tile t ph1/ph2 -> stage (t+1).A0/A1 (opposite buffer, idle)
//   tile t ph3/ph4 -> stage (t+2).B0/B1 (own buffer; B last read ph2)
// vmcnt(4) at tile end drains through (t+1).A1 -> next tile fully landed.
// ---------------------------------------------------------------------------
template <int OFS>
__device__ __forceinline__ bf16x8 ds128(uint32_t a) {
  bf16x8 r;
  asm volatile("ds_read_b128 %0, %1 offset:%2" : "=v"(r) : "v"(a), "n"(OFS));
  return r;
}

// A fragments af[i][ks]: byte offset BUF*32768 + MH*8192 + i*2048 from base[ks]
template <int BUF, int MH>
__device__ __forceinline__ void rdA(bf16x8 (&af)[4][2], uint32_t a0, uint32_t a1) {
  af[0][0] = ds128<BUF * 32768 + MH * 8192 + 0>(a0);
  af[0][1] = ds128<BUF * 32768 + MH * 8192 + 0>(a1);
  af[1][0] = ds128<BUF * 32768 + MH * 8192 + 2048>(a0);
  af[1][1] = ds128<BUF * 32768 + MH * 8192 + 2048>(a1);
  af[2][0] = ds128<BUF * 32768 + MH * 8192 + 4096>(a0);
  af[2][1] = ds128<BUF * 32768 + MH * 8192 + 4096>(a1);
  af[3][0] = ds128<BUF * 32768 + MH * 8192 + 6144>(a0);
  af[3][1] = ds128<BUF * 32768 + MH * 8192 + 6144>(a1);
}

// B fragments bf[j][ks]: byte offset BUF*32768 + NH*4096 + j*2048 from base[ks]
template <int BUF, int NH>
__device__ __forceinline__ void rdB(bf16x8 (&bfr)[2][2], uint32_t b0, uint32_t b1) {
  bfr[0][0] = ds128<BUF * 32768 + NH * 4096 + 0>(b0);
  bfr[0][1] = ds128<BUF * 32768 + NH * 4096 + 0>(b1);
  bfr[1][0] = ds128<BUF * 32768 + NH * 4096 + 2048>(b0);
  bfr[1][1] = ds128<BUF * 32768 + NH * 4096 + 2048>(b1);
}

template <int MH, int NH>
__device__ __forceinline__ void mfma16x(f32x4 (&acc)[8][4], bf16x8 (&af)[4][2],
                                        bf16x8 (&bfr)[2][2]) {
  __builtin_amdgcn_s_setprio(1);
#pragma unroll
  for (int i = 0; i < 4; ++i)
#pragma unroll
    for (int j = 0; j < 2; ++j)
#pragma unroll
      for (int ks = 0; ks < 2; ++ks)
        acc[MH * 4 + i][NH * 2 + j] = __builtin_amdgcn_mfma_f32_16x16x32_bf16(
            af[i][ks], bfr[j][ks], acc[MH * 4 + i][NH * 2 + j], 0, 0, 0);
  __builtin_amdgcn_s_setprio(0);
}

__device__ __forceinline__ void gemm256_core(
    const bf16* __restrict__ A, const bf16* __restrict__ Bt, int K,
    int m0, int n0, bf16* As, bf16* Bs, f32x4 (&acc)[8][4]) {
  const int t = threadIdx.x;          // 0..511
  const int lane = t & 63;
  const int wave = t >> 6;            // 0..7
  const int wr = wave >> 2;           // 0..1 (M)
  const int wc = wave & 3;            // 0..3 (N)
  const int l15 = lane & 15;
  const int quad = lane >> 4;

  // Staging: chunk c = p*512+t covers 16B; row r = c>>3 (0..127 within half),
  // slot s = c&7 stores k-group g = s ^ (r&7) (pre-swizzled global source).
  const bf16* gA[2];
  const bf16* gB[2];
  int lOff[2];
#pragma unroll
  for (int p = 0; p < 2; ++p) {
    int c = p * 512 + t;
    int r = c >> 3;
    int g = (c & 7) ^ (r & 7);
    gA[p] = A + (size_t)(m0 + r) * K + g * 8;
    gB[p] = Bt + (size_t)(n0 + r) * K + g * 8;
    lOff[p] = c * 16;
  }
  const size_t rowH = (size_t)128 * K;  // elements: half-tile row step

  auto stA = [&](int tile, int h) {
#pragma unroll
    for (int p = 0; p < 2; ++p)
      async16(gA[p] + (size_t)h * rowH + tile * 64,
              (char*)As + (tile & 1) * 32768 + h * 16384 + lOff[p]);
  };
  auto stB = [&](int tile, int h) {
#pragma unroll
    for (int p = 0; p < 2; ++p)
      async16(gB[p] + (size_t)h * rowH + tile * 64,
              (char*)Bs + (tile & 1) * 32768 + h * 16384 + lOff[p]);
  };

  // Hoisted swizzled read bases (swizzle (ks*4+quad)^(l15&7) is row-invariant)
  const int swz0 = ((0 * 4 + quad) ^ (l15 & 7)) * 16;  // bytes
  const int swz1 = ((1 * 4 + quad) ^ (l15 & 7)) * 16;
  const uint32_t aB0 = laddr(As) + (uint32_t)((wr * 128 + l15) * 128 + swz0);
  const uint32_t aB1 = laddr(As) + (uint32_t)((wr * 128 + l15) * 128 + swz1);
  const uint32_t bB0 = laddr(Bs) + (uint32_t)((wc * 64 + l15) * 128 + swz0);
  const uint32_t bB1 = laddr(Bs) + (uint32_t)((wc * 64 + l15) * 128 + swz1);

#pragma unroll
  for (int i = 0; i < 8; ++i)
#pragma unroll
    for (int j = 0; j < 4; ++j) acc[i][j] = (f32x4){0.f, 0.f, 0.f, 0.f};

  const int NT = K >> 6;   // K / 64 (even)
  const int NI = NT >> 1;

  // Prologue: tile0 {B0,B1,A0,A1} + tile1 {B0,B1}; wait tile0 (leave 4 loads).
  stB(0, 0); stB(0, 1); stA(0, 0); stA(0, 1);
  stB(1, 0); stB(1, 1);
  asm volatile("s_waitcnt vmcnt(4)");
  hbar();

  bf16x8 aF[4][2], bF0[2][2], bF1[2][2];

  for (int it = 0; it < NI; ++it) {
    const int t0 = 2 * it;
    const bool more = (it + 1 < NI);

    // ---- tile t0 (buf 0) ----
    rdA<0, 0>(aF, aB0, aB1);                 // ph1: 12 ds_reads
    rdB<0, 0>(bF0, bB0, bB1);
    stA(t0 + 1, 0);
    asm volatile("s_waitcnt lgkmcnt(8)");
    hbar();
    wait_lgkm0();
    mfma16x<0, 0>(acc, aF, bF0);
    hbar();

    rdB<0, 1>(bF1, bB0, bB1);                // ph2: 4 ds_reads
    stA(t0 + 1, 1);
    hbar();
    wait_lgkm0();
    mfma16x<0, 1>(acc, aF, bF1);
    hbar();

    rdA<0, 1>(aF, aB0, aB1);                 // ph3: 8 ds_reads
    if (more) stB(t0 + 2, 0);
    hbar();
    wait_lgkm0();
    mfma16x<1, 0>(acc, aF, bF0);
    hbar();

    if (more) stB(t0 + 2, 1);                // ph4
    hbar();
    mfma16x<1, 1>(acc, aF, bF1);
    SBAR0();
    if (more) { asm volatile("s_waitcnt vmcnt(4)"); }
    else      { asm volatile("s_waitcnt vmcnt(0)"); }
    hbar();

    // ---- tile t0+1 (buf 1) ----
    rdA<1, 0>(aF, aB0, aB1);                 // ph5
    rdB<1, 0>(bF0, bB0, bB1);
    if (more) stA(t0 + 2, 0);
    asm volatile("s_waitcnt lgkmcnt(8)");
    hbar();
    wait_lgkm0();
    mfma16x<0, 0>(acc, aF, bF0);
    hbar();

    rdB<1, 1>(bF1, bB0, bB1);                // ph6
    if (more) stA(t0 + 2, 1);
    hbar();
    wait_lgkm0();
    mfma16x<0, 1>(acc, aF, bF1);
    hbar();

    rdA<1, 1>(aF, aB0, aB1);                 // ph7
    if (more) stB(t0 + 3, 0);
    hbar();
    wait_lgkm0();
    mfma16x<1, 0>(acc, aF, bF0);
    hbar();

    if (more) stB(t0 + 3, 1);                // ph8
    hbar();
    mfma16x<1, 1>(acc, aF, bF1);
    SBAR0();
    if (more) { asm volatile("s_waitcnt vmcnt(4)"); }
    hbar();
  }
}

template <int ACT>
__global__ __launch_bounds__(512, 2) void gemm256(
    const bf16* __restrict__ A, const bf16* __restrict__ Bt,
    const bf16* __restrict__ bias, bf16* __restrict__ C,
    int M, int N, int K, const int* __restrict__ gate) {
  if (gate && *gate == 0) return;
  __shared__ __align__(16) bf16 As[2 * 16384];
  __shared__ __align__(16) bf16 Bs[2 * 16384];
  const int m0 = blockIdx.y * 256;
  const int n0 = blockIdx.x * 256;
  f32x4 acc[8][4];
  gemm256_core(A, Bt, K, m0, n0, As, Bs, acc);

  const int lane = threadIdx.x & 63;
  const int wave = threadIdx.x >> 6;
  const int wr = wave >> 2;
  const int wc = wave & 3;
  const int l15 = lane & 15;
  const int quad = lane >> 4;
  float bv[4];
#pragma unroll
  for (int j = 0; j < 4; ++j) bv[j] = bf2f(bias[n0 + wc * 64 + j * 16 + l15]);
  // j innermost: each row's 4x32B segments issue back-to-back (full sectors)
#pragma unroll
  for (int i = 0; i < 8; ++i) {
#pragma unroll
    for (int r = 0; r < 4; ++r) {
      int row = m0 + wr * 128 + i * 16 + quad * 4 + r;
#pragma unroll
      for (int j = 0; j < 4; ++j) {
        int col = n0 + wc * 64 + j * 16 + l15;
        float v = acc[i][j][r] + bv[j];
        if (ACT == 1) v = gelu_f(v);
        C[(size_t)row * N + col] = f2bf(v);
      }
    }
  }
  (void)M;
}

// sim variant: acc = q @ keys^T; epilogue scales by rsqrt(qsum)*kscale,
// packed-max reduce per row (hi=ordered float, lo=~idx) via u64 atomicMax.
__global__ __launch_bounds__(512, 2) void gemm256_sim(
    const bf16* __restrict__ Q, const bf16* __restrict__ Kb,
    const float* __restrict__ qsum, const float* __restrict__ kscale,
    unsigned long long* __restrict__ amax, int M, int N, int K,
    const int* __restrict__ gate) {
  if (*gate == 0) return;
  __shared__ __align__(16) bf16 As[2 * 16384];
  __shared__ __align__(16) bf16 Bs[2 * 16384];
  const int m0 = blockIdx.y * 256;
  const int n0 = blockIdx.x * 256;
  f32x4 acc[8][4];
  gemm256_core(Q, Kb, K, m0, n0, As, Bs, acc);

  const int lane = threadIdx.x & 63;
  const int wave = threadIdx.x >> 6;
  const int wr = wave >> 2;
  const int wc = wave & 3;
  const int l15 = lane & 15;
  const int quad = lane >> 4;

  float ks4[4];
#pragma unroll
  for (int j = 0; j < 4; ++j) ks4[j] = kscale[n0 + wc * 64 + j * 16 + l15];

#pragma unroll
  for (int i = 0; i < 8; ++i) {
#pragma unroll
    for (int r = 0; r < 4; ++r) {
      int row = m0 + wr * 128 + i * 16 + quad * 4 + r;
      float qs = rsqrtf(fmaxf(qsum[row], 1e-16f));  // == 1/max(norm,1e-8)
      float best = -1e30f;
      int bidx = 0;
#pragma unroll
      for (int j = 0; j < 4; ++j) {
        int col = n0 + wc * 64 + j * 16 + l15;
        float v = acc[i][j][r] * qs * ks4[j];
        if (v > best) { best = v; bidx = col; }
      }
      unsigned int u = __float_as_uint(best);
      unsigned int ou = (u & 0x80000000u) ? ~u : (u | 0x80000000u);
      unsigned long long pk =
          ((unsigned long long)ou << 32) |
          (unsigned long long)(0xFFFFFFFFu - (unsigned int)bidx);
#pragma unroll
      for (int m = 1; m < 16; m <<= 1) {
        unsigned long long o = (unsigned long long)__shfl_xor((long long)pk, m, 64);
        if (o > pk) pk = o;
      }
      if (l15 == 0) atomicMax(amax + row, pk);
    }
  }
  (void)M;
}

// 64x64-tile conf-net GEMM. ZSUM: block (0,0) thread 0 zeroes the cmean
// accumulator (dispatch ordering puts this strictly before conf_head_reduce).
template <int ACT>
__global__ __launch_bounds__(256, 2) void gemm64(
    const bf16* __restrict__ A, const bf16* __restrict__ Bt,
    const bf16* __restrict__ bias, bf16* __restrict__ C,
    float* __restrict__ zsum, int M, int N, int K,
    const int* __restrict__ gate) {
  if (gate && *gate == 0) return;
  if (zsum && blockIdx.x == 0 && blockIdx.y == 0 && threadIdx.x == 0)
    *zsum = 0.f;
  __shared__ __align__(16) bf16 As[64 * 64];
  __shared__ __align__(16) bf16 Bs[64 * 64];

  const int t = threadIdx.x;
  const int lane = t & 63;
  const int wave = t >> 6;
  const int m0 = blockIdx.y * 64;
  const int n0 = blockIdx.x * 64;

  const bf16* gA[2];
  const bf16* gB[2];
  int lOff[2];
#pragma unroll
  for (int p = 0; p < 2; ++p) {
    int c = p * 256 + t;
    int r = c >> 3;
    int g = (c & 7) ^ (r & 7);
    gA[p] = A + (size_t)(m0 + r) * K + g * 8;
    gB[p] = Bt + (size_t)(n0 + r) * K + g * 8;
    lOff[p] = c * 16;
  }

  f32x4 acc[2][2];
#pragma unroll
  for (int i = 0; i < 2; ++i)
#pragma unroll
    for (int j = 0; j < 2; ++j) acc[i][j] = (f32x4){0.f, 0.f, 0.f, 0.f};

  const int wrow = (wave >> 1) * 32;
  const int wcol = (wave & 1) * 32;
  const int l15 = lane & 15;
  const int quad = lane >> 4;

  for (int kt = 0; kt < K; kt += 64) {
#pragma unroll
    for (int p = 0; p < 2; ++p) {
      async16(gA[p], (char*)As + lOff[p]);
      async16(gB[p], (char*)Bs + lOff[p]);
      gA[p] += 64;
      gB[p] += 64;
    }
    asm volatile("s_waitcnt vmcnt(0)" ::: "memory");
    __syncthreads();
#pragma unroll
    for (int ks = 0; ks < 2; ++ks) {
      bf16x8 af[2], bfv[2];
#pragma unroll
      for (int i = 0; i < 2; ++i) {
        int ra = wrow + i * 16 + l15;
        int g = ks * 4 + quad;
        af[i] = *(const bf16x8*)(As + ra * 64 + ((g ^ (ra & 7)) * 8));
        int rb = wcol + i * 16 + l15;
        bfv[i] = *(const bf16x8*)(Bs + rb * 64 + ((g ^ (rb & 7)) * 8));
      }
#pragma unroll
      for (int i = 0; i < 2; ++i)
#pragma unroll
        for (int j = 0; j < 2; ++j)
          acc[i][j] = __builtin_amdgcn_mfma_f32_16x16x32_bf16(af[i], bfv[j],
                                                              acc[i][j], 0, 0, 0);
    }
    __syncthreads();
  }

#pragma unroll
  for (int j = 0; j < 2; ++j) {
    int col = n0 + wcol + j * 16 + l15;
    float bv = bf2f(bias[col]);
#pragma unroll
    for (int i = 0; i < 2; ++i) {
#pragma unroll
      for (int r = 0; r < 4; ++r) {
        int row = m0 + wrow + i * 16 + quad * 4 + r;
        float v = acc[i][j][r] + bv;
        if (ACT == 1) v = gelu_f(v);
        C[(size_t)row * N + col] = f2bf(v);
      }
    }
  }
}

// --- small kernels ---------------------------------------------------------

__global__ void transpose_any(const void* __restrict__ src, bf16* __restrict__ dst,
                              int R, int C, const int* __restrict__ flag) {
  __shared__ bf16 tile[64][65];
  const int isf = *flag;
  int c0 = blockIdx.x * 64, r0 = blockIdx.y * 64;
#pragma unroll 4
  for (int p = 0; p < 16; ++p) {
    int idx = p * 256 + threadIdx.x;
    int r = idx >> 6, c = idx & 63;
    size_t si = (size_t)(r0 + r) * C + (c0 + c);
    tile[r][c] = isf ? f2bf(((const float*)src)[si]) : ((const bf16*)src)[si];
  }
  __syncthreads();
#pragma unroll 4
  for (int p = 0; p < 16; ++p) {
    int idx = p * 256 + threadIdx.x;
    int r = idx >> 6, c = idx & 63;
    dst[(size_t)(c0 + r) * R + (r0 + c)] = tile[c][r];
  }
}

__global__ void key_scale(const bf16* __restrict__ keys, const void* __restrict__ usage,
                          float* __restrict__ kscale, int cols,
                          const int* __restrict__ flag) {
  int row = blockIdx.x;
  const bf16* xr = keys + (size_t)row * cols;
  float s = 0.f;
  for (int i = threadIdx.x * 8; i < cols; i += 256 * 8) {
    union { uint4 u; bf16 h[8]; } u;
    u.u = *(const uint4*)(xr + i);
#pragma unroll
    for (int j = 0; j < 8; ++j) { float f = bf2f(u.h[j]); s += f * f; }
  }
  __shared__ float red[256];
  red[threadIdx.x] = s;
  __syncthreads();
  for (int k = 128; k > 0; k >>= 1) {
    if (threadIdx.x < k) red[threadIdx.x] += red[threadIdx.x + k];
    __syncthreads();
  }
  if (threadIdx.x == 0) {
    float us = *flag ? ((const float*)usage)[row] : bf2f(((const bf16*)usage)[row]);
    kscale[row] = us / fmaxf(sqrtf(red[0]), 1e-8f);
  }
}

// per-row conf head + per-block partial of sum(conf) -> one atomicAdd/block
__global__ void conf_head_reduce(const bf16* __restrict__ h2,
                                 const bf16* __restrict__ w3,
                                 const bf16* __restrict__ b3,
                                 const bf16* __restrict__ slope,
                                 const bf16* __restrict__ cbias,
                                 float* __restrict__ conf,
                                 float* __restrict__ csum,
                                 const int* __restrict__ gate) {
  if (gate && *gate == 0) return;
  int wave = threadIdx.x >> 6, lane = threadIdx.x & 63;
  int row = blockIdx.x * 4 + wave;
  const bf16* hr = h2 + (size_t)row * CH2_DIM;
  float s = bf2f(hr[lane]) * bf2f(w3[lane]) +
            bf2f(hr[lane + 64]) * bf2f(w3[lane + 64]);
  for (int m = 32; m > 0; m >>= 1) s += __shfl_xor(s, m, 64);
  __shared__ float part[4];
  if (lane == 0) {
    float raw = sigmoid_f(s + bf2f(b3[0]));
    float c = sigmoid_f(bf2f(slope[0]) * (raw - 0.5f) + bf2f(cbias[0]));
    conf[row] = c;
    part[wave] = c;
  }
  __syncthreads();
  if (threadIdx.x == 0)
    atomicAdd(csum, part[0] + part[1] + part[2] + part[3]);
}

// ctrl: [0]=adaptive_max_depth, [1]=depth, [2]=stopped, [3..7]=do_compute[d]
__global__ void init_control(const float* __restrict__ csum, int* __restrict__ ctrl) {
  float cf = 1.0f - (*csum / (float)B_DIM);
  int amd = 1 + (int)(cf * 4.0f);  // truncation matches .astype(int32)
  if (amd > 5) amd = 5;
  ctrl[0] = amd;
  ctrl[1] = 0;
  ctrl[2] = 0;
}

// control step + unconditional clear of lookup accumulators (grid B/256)
__global__ void step_control(const float* __restrict__ csum, int* __restrict__ ctrl,
                             int d, unsigned long long* __restrict__ amax,
                             float* __restrict__ qsum, int n) {
  int i = blockIdx.x * 256 + threadIdx.x;
  if (i < n) { amax[i] = 0ull; qsum[i] = 0.f; }
  if (i == 0) {
    int amd = ctrl[0], depth = ctrl[1], stopped = ctrl[2];
    bool brk = ((*csum / (float)B_DIM) >= 0.85f);
    bool active = (!stopped) && (d < amd);
    if (active) depth = d + 1;
    ctrl[3 + d] = (active && !brk) ? 1 : 0;
    if (active && brk) stopped = 1;
    ctrl[1] = depth;
    ctrl[2] = stopped;
  }
}

// in-place: replace S row with mem_values row only when best_sim > 0.9
__global__ void select_mem(const unsigned long long* __restrict__ amax,
                           const void* __restrict__ mv, bf16* __restrict__ S,
                           int Hc, const int* __restrict__ gate,
                           const int* __restrict__ flag) {
  if (*gate == 0) return;
  int b = blockIdx.x;
  unsigned long long pk = amax[b];
  unsigned int ou = (unsigned int)(pk >> 32);
  if (!(ou > 0xBF666666u)) return;  // ordered(0.9f); strict >
  int idx = (int)(0xFFFFFFFFu - (unsigned int)(pk & 0xFFFFFFFFull));
  bf16* dst = S + (size_t)b * Hc;
  if (*flag) {
    const float* src = (const float*)mv + (size_t)idx * Hc;
    for (int i = threadIdx.x; i < Hc; i += 256) dst[i] = f2bf(src[i]);
  } else {
    const uint4* src = (const uint4*)((const bf16*)mv + (size_t)idx * Hc);
    for (int i = threadIdx.x; i < Hc / 8; i += 256) ((uint4*)dst)[i] = src[i];
  }
}

__global__ void emit_state(const bf16* __restrict__ S, void* __restrict__ out,
                           int n, const int* __restrict__ flag) {
  int i = blockIdx.x * 256 + threadIdx.x;
  if (i >= n) return;
  if (*flag) ((float*)out)[i] = bf2f(S[i]);
  else       ((bf16*)out)[i] = S[i];
}

__global__ void write_tail(const float* __restrict__ conf, const int* __restrict__ ctrl,
                           void* __restrict__ out, int bh, int n,
                           const int* __restrict__ flag) {
  int i = blockIdx.x * 256 + threadIdx.x;
  if (i >= n) return;
  if (*flag) {
    ((float*)out)[bh + 1 + i] = conf[i];
    if (i == 0) ((float*)out)[bh] = (float)ctrl[1];
  } else {
    ((bf16*)out)[bh + 1 + i] = f2bf(conf[i]);
    if (i == 0) ((bf16*)out)[bh] = f2bf((float)ctrl[1]);
  }
}

// ---------------------------------------------------------------------------

extern "C" void kernel_launch(void* const* d_in, const int* in_sizes, int n_in,
                              void* d_out, int out_size, void* d_ws, size_t ws_size,
                              hipStream_t stream) {
  const int B = B_DIM, H = H_DIM, H2 = 2 * H_DIM, C1 = CH1_DIM, C2 = CH2_DIM,
            NM = NMEM_DIM;
  const void* x = d_in[0];
  const void* cw1 = d_in[1];
  const void* cb1 = d_in[2];
  const void* cw2 = d_in[3];
  const void* cb2 = d_in[4];
  const void* cw3 = d_in[5];
  const void* cb3 = d_in[6];
  const void* cal_slope = d_in[7];
  const void* cal_bias = d_in[8];
  const void* rw1 = d_in[9];
  const void* rb1 = d_in[10];
  const void* rw2 = d_in[11];
  const void* rb2 = d_in[12];
  const void* mqw = d_in[13];
  const void* mqb = d_in[14];
  const void* mem_keys = d_in[15];
  const void* mem_values = d_in[16];
  const void* mem_usage = d_in[17];

  char* ws = (char*)d_ws;
  size_t off = 0;
  auto alloc = [&](size_t bytes) -> char* {
    char* p = ws + off;
    off = (off + bytes + 255) & ~(size_t)255;
    return p;
  };
  bf16* rw1t = (bf16*)alloc((size_t)H2 * H * 2);
  bf16* rw2t = (bf16*)alloc((size_t)H * H2 * 2);
  bf16* mqwt = (bf16*)alloc((size_t)H * H * 2);
  bf16* cw1t = (bf16*)alloc((size_t)C1 * H * 2);
  bf16* cw2t = (bf16*)alloc((size_t)C2 * C1 * 2);
  bf16* keysb = (bf16*)alloc((size_t)NM * H * 2);
  bf16* S = (bf16*)alloc((size_t)B * H * 2);
  bf16* Hbuf = (bf16*)alloc((size_t)B * H2 * 2);  // q aliases lower half
  bf16* q = Hbuf;
  bf16* h1 = (bf16*)alloc((size_t)B * C1 * 2);
  bf16* h2 = (bf16*)alloc((size_t)B * C2 * 2);
  bf16* rb1b = (bf16*)alloc((size_t)H2 * 2);
  bf16* rb2b = (bf16*)alloc((size_t)H * 2);
  bf16* mqbb = (bf16*)alloc((size_t)H * 2);
  bf16* cb1b = (bf16*)alloc((size_t)C1 * 2);
  bf16* cb2b = (bf16*)alloc((size_t)C2 * 2);
  bf16* cw3b = (bf16*)alloc((size_t)C2 * 2);
  bf16* cb3b = (bf16*)alloc(256);
  bf16* slopeb = (bf16*)alloc(256);
  bf16* cbiasb = (bf16*)alloc(256);
  float* conf = (float*)alloc((size_t)B * 4);
  float* qsum = (float*)alloc((size_t)B * 4);
  float* kscale = (float*)alloc((size_t)NM * 4);
  unsigned long long* amax = (unsigned long long*)alloc((size_t)B * 8);
  float* csum = (float*)alloc(256);
  int* ctrl = (int*)alloc(256);
  int* dflag = (int*)alloc(256);
  (void)ws_size; (void)n_in; (void)in_sizes; (void)out_size;

  dim3 blk(256);
  dim3 blk512(512);

  // --- dtype probe ---
  flag_init<<<1, 1, 0, stream>>>(dflag);
  probe_dtype<<<64, blk, 0, stream>>>(x, dflag);

  // --- ingest to bf16 ---
  ingest<<<(B * H + 255) / 256, blk, 0, stream>>>(x, S, B * H, dflag);
  ingest<<<(NM * H + 255) / 256, blk, 0, stream>>>(mem_keys, keysb, NM * H, dflag);
  SmallJobs sj;
  sj.src[0] = rb1;       sj.dst[0] = rb1b;   sj.n[0] = H2;
  sj.src[1] = rb2;       sj.dst[1] = rb2b;   sj.n[1] = H;
  sj.src[2] = mqb;       sj.dst[2] = mqbb;   sj.n[2] = H;
  sj.src[3] = cb1;       sj.dst[3] = cb1b;   sj.n[3] = C1;
  sj.src[4] = cb2;       sj.dst[4] = cb2b;   sj.n[4] = C2;
  sj.src[5] = cw3;       sj.dst[5] = cw3b;   sj.n[5] = C2;
  sj.src[6] = cb3;       sj.dst[6] = cb3b;   sj.n[6] = 1;
  sj.src[7] = cal_slope; sj.dst[7] = slopeb; sj.n[7] = 1;
  sj.src[8] = cal_bias;  sj.dst[8] = cbiasb; sj.n[8] = 1;
  ingest_small<<<9, blk, 0, stream>>>(sj, dflag);

  // --- weight transposes (B^T form for GEMM) + key scales ---
  transpose_any<<<dim3(H2 / 64, H / 64), blk, 0, stream>>>(rw1, rw1t, H, H2, dflag);
  transpose_any<<<dim3(H / 64, H2 / 64), blk, 0, stream>>>(rw2, rw2t, H2, H, dflag);
  transpose_any<<<dim3(H / 64, H / 64), blk, 0, stream>>>(mqw, mqwt, H, H, dflag);
  transpose_any<<<dim3(C1 / 64, H / 64), blk, 0, stream>>>(cw1, cw1t, H, C1, dflag);
  transpose_any<<<dim3(C2 / 64, C1 / 64), blk, 0, stream>>>(cw2, cw2t, C1, C2, dflag);
  key_scale<<<NM, blk, 0, stream>>>(keysb, mem_usage, kscale, H, dflag);

  auto conf_pipe = [&](const bf16* Sin, const int* gate) {
    gemm64<1><<<dim3(C1 / 64, B / 64), blk, 0, stream>>>(Sin, cw1t, cb1b, h1,
                                                         csum, B, C1, H, gate);
    gemm64<1><<<dim3(C2 / 64, B / 64), blk, 0, stream>>>(h1, cw2t, cb2b, h2,
                                                         nullptr, B, C2, C1, gate);
    conf_head_reduce<<<B / 4, blk, 0, stream>>>(h2, cw3b, cb3b, slopeb, cbiasb,
                                                conf, csum, gate);
  };

  conf_pipe(S, nullptr);
  init_control<<<1, 1, 0, stream>>>(csum, ctrl);

  for (int d = 0; d < 5; ++d) {
    step_control<<<B / 256, blk, 0, stream>>>(csum, ctrl, d, amax, qsum, B);
    const int* gate = ctrl + 3 + d;
    if (d >= 1) {
      gemm_bt<128, 0, 1><<<dim3(H / 128, B / 128), blk, 0, stream>>>(
          S, mqwt, mqbb, q, qsum, B, H, H, gate);
      gemm256_sim<<<dim3(NM / 256, B / 256), blk512, 0, stream>>>(
          q, keysb, qsum, kscale, amax, B, NM, H, gate);
      select_mem<<<B, blk, 0, stream>>>(amax, mem_values, S, H, gate, dflag);
    }
    gemm256<1><<<dim3(H2 / 256, B / 256), blk512, 0, stream>>>(
        S, rw1t, rb1b, Hbuf, B, H2, H, gate);
    gemm_bt<128, 0, 0><<<dim3(H / 128, B / 128), blk, 0, stream>>>(
        Hbuf, rw2t, rb2b, S, nullptr, B, H, H2, gate);
    conf_pipe(S, gate);
  }

  emit_state<<<(B * H + 255) / 256, blk, 0, stream>>>(S, d_out, B * H, dflag);
  write_tail<<<B / 256, blk, 0, stream>>>(conf, ctrl, d_out, B * H, B, dflag);
}

// Round 4
// 873.639 us; speedup vs baseline: 1.0133x; 1.0133x over previous
//
#include <hip/hip_runtime.h>
#include <hip/hip_bf16.h>
#include <stdint.h>

typedef __hip_bfloat16 bf16;
typedef __attribute__((ext_vector_type(8))) short bf16x8;   // 8 bf16 = 4 VGPR
typedef __attribute__((ext_vector_type(4))) float f32x4;

#define B_DIM 4096
#define H_DIM 2048
#define CH1_DIM 256
#define CH2_DIM 128
#define NMEM_DIM 4096

__device__ __forceinline__ float bf2f(bf16 v) { return __bfloat162float(v); }
__device__ __forceinline__ bf16 f2bf(float v) { return __float2bfloat16(v); }

__device__ __forceinline__ float gelu_f(float x) {
  float u = 0.7978845608028654f * (x + 0.044715f * x * x * x);
  float t = 1.0f - 2.0f / (__expf(2.0f * u) + 1.0f);
  return 0.5f * x * (1.0f + t);
}
__device__ __forceinline__ float sigmoid_f(float x) {
  return 1.0f / (1.0f + __expf(-x));
}

__device__ __forceinline__ void async16(const void* g, void* l) {
  __builtin_amdgcn_global_load_lds(
      (const __attribute__((address_space(1))) char*)(uintptr_t)g,
      (__attribute__((address_space(3))) char*)(uintptr_t)l, 16, 0, 0);
}

// XCD-chunked blockIdx swizzle (T1): dispatch round-robins wgid across 8 XCDs;
// remap so each XCD owns a contiguous chunk of tiles (A-panels L2-resident).
// Valid only when nwg % 8 == 0 (all our grids satisfy this).
__device__ __forceinline__ void xcd_swizzle(int& bx, int& by) {
  int gx = gridDim.x;
  int nwg = gx * gridDim.y;
  if ((nwg & 7) == 0) {
    int wg = by * gx + bx;
    wg = (wg & 7) * (nwg >> 3) + (wg >> 3);
    bx = wg % gx;
    by = wg / gx;
  }
}

// ---------------------------------------------------------------------------
// dtype probe: flag=1 -> inputs are float32, flag=0 -> bfloat16.
// ---------------------------------------------------------------------------
__global__ void flag_init(int* flag) { *flag = 0; }

__global__ void probe_dtype(const void* x, int* flag) {
  const unsigned short* u = (const unsigned short*)x;
  int i0 = blockIdx.x * 256 + threadIdx.x;
  bool big = false;
#pragma unroll
  for (int k = 0; k < 16; ++k) {
    unsigned short h = u[(size_t)(i0 * 16 + k) * 2];  // even bf16-view index
    unsigned int e = (h >> 7) & 0xFF;
    if (e >= 0x9A) big = true;  // |v| >= 2^27 or inf/nan -> f32 mantissa noise
  }
  if (big) atomicOr(flag, 1);
}

__global__ void ingest(const void* src, bf16* dst, int n, const int* flag) {
  int i = blockIdx.x * 256 + threadIdx.x;
  if (i >= n) return;
  if (*flag) dst[i] = f2bf(((const float*)src)[i]);
  else       dst[i] = ((const bf16*)src)[i];
}

struct SmallJobs { const void* src[9]; bf16* dst[9]; int n[9]; };
__global__ void ingest_small(SmallJobs jobs, const int* flag) {
  int b = blockIdx.x;
  const void* src = jobs.src[b];
  bf16* dst = jobs.dst[b];
  int n = jobs.n[b];
  bool isf = *flag != 0;
  for (int i = threadIdx.x; i < n; i += 256)
    dst[i] = isf ? f2bf(((const float*)src)[i]) : ((const bf16*)src)[i];
}

// ---------------------------------------------------------------------------
// 128^2-tile GEMM (Round-2 verified geometry, + XCD swizzle).
// ---------------------------------------------------------------------------
template <int BT, int ACT, int STAT>
__global__ __launch_bounds__(256, 2) void gemm_bt(
    const bf16* __restrict__ A, const bf16* __restrict__ Bt,
    const bf16* __restrict__ bias, bf16* __restrict__ C,
    float* __restrict__ qsum, int M, int N, int K,
    const int* __restrict__ gate) {
  if (gate && *gate == 0) return;
  constexpr int CH = BT / 32;
  constexpr int FR = BT / 32;
  __shared__ __align__(16) bf16 As[BT * 64];
  __shared__ __align__(16) bf16 Bs[BT * 64];

  const int t = threadIdx.x;
  const int lane = t & 63;
  const int wave = t >> 6;
  int bx = blockIdx.x, by = blockIdx.y;
  xcd_swizzle(bx, by);
  const int m0 = by * BT;
  const int n0 = bx * BT;

  const bf16* gA[CH];
  const bf16* gB[CH];
  int lOff[CH];
#pragma unroll
  for (int p = 0; p < CH; ++p) {
    int c = p * 256 + t;
    int r = c >> 3;
    int g = (c & 7) ^ (r & 7);  // logical k-group stored at this slot
    gA[p] = A + (size_t)(m0 + r) * K + g * 8;
    gB[p] = Bt + (size_t)(n0 + r) * K + g * 8;
    lOff[p] = c * 16;
  }

  f32x4 acc[FR][FR];
#pragma unroll
  for (int i = 0; i < FR; ++i)
#pragma unroll
    for (int j = 0; j < FR; ++j) acc[i][j] = (f32x4){0.f, 0.f, 0.f, 0.f};

  const int wrow = (wave >> 1) * (FR * 16);
  const int wcol = (wave & 1) * (FR * 16);
  const int l15 = lane & 15;
  const int quad = lane >> 4;

  for (int kt = 0; kt < K; kt += 64) {
#pragma unroll
    for (int p = 0; p < CH; ++p) {
      async16(gA[p], (char*)As + lOff[p]);
      async16(gB[p], (char*)Bs + lOff[p]);
      gA[p] += 64;
      gB[p] += 64;
    }
    asm volatile("s_waitcnt vmcnt(0)" ::: "memory");
    __syncthreads();
#pragma unroll
    for (int ks = 0; ks < 2; ++ks) {
      bf16x8 af[FR], bfv[FR];
#pragma unroll
      for (int i = 0; i < FR; ++i) {
        int ra = wrow + i * 16 + l15;
        int g = ks * 4 + quad;
        af[i] = *(const bf16x8*)(As + ra * 64 + ((g ^ (ra & 7)) * 8));
        int rb = wcol + i * 16 + l15;
        bfv[i] = *(const bf16x8*)(Bs + rb * 64 + ((g ^ (rb & 7)) * 8));
      }
#pragma unroll
      for (int i = 0; i < FR; ++i)
#pragma unroll
        for (int j = 0; j < FR; ++j)
          acc[i][j] = __builtin_amdgcn_mfma_f32_16x16x32_bf16(af[i], bfv[j],
                                                              acc[i][j], 0, 0, 0);
    }
    __syncthreads();
  }

  if constexpr (STAT == 0) {
#pragma unroll
    for (int j = 0; j < FR; ++j) {
      int col = n0 + wcol + j * 16 + l15;
      float bv = bf2f(bias[col]);
#pragma unroll
      for (int i = 0; i < FR; ++i) {
#pragma unroll
        for (int r = 0; r < 4; ++r) {
          int row = m0 + wrow + i * 16 + quad * 4 + r;
          float v = acc[i][j][r] + bv;
          if (ACT == 1) v = gelu_f(v);
          C[(size_t)row * N + col] = f2bf(v);
        }
      }
    }
  } else {
    float bv[FR];
#pragma unroll
    for (int j = 0; j < FR; ++j) bv[j] = bf2f(bias[n0 + wcol + j * 16 + l15]);
#pragma unroll
    for (int i = 0; i < FR; ++i) {
#pragma unroll
      for (int r = 0; r < 4; ++r) {
        int row = m0 + wrow + i * 16 + quad * 4 + r;
        float ss = 0.f;
#pragma unroll
        for (int j = 0; j < FR; ++j) {
          int col = n0 + wcol + j * 16 + l15;
          float v = acc[i][j][r] + bv[j];
          if (ACT == 1) v = gelu_f(v);
          C[(size_t)row * N + col] = f2bf(v);
          ss += v * v;
        }
#pragma unroll
        for (int m = 1; m < 16; m <<= 1) ss += __shfl_xor(ss, m, 64);
        if (l15 == 0) atomicAdd(qsum + row, ss);
      }
    }
  }
}

// ---------------------------------------------------------------------------
// 256^2-tile 8-phase GEMM core, v3 (resubmitted; r3 bench was an infra
// failure, not a kernel failure — schedule re-audited: vmcnt accounting,
// WAR slotting, OOB, swizzle bijection all verified):
//  - compiler-visible C++ ds_reads off precomputed row-invariant swizzled
//    bases (r2 proved asm reads + sched_barrier pinning costs 25%)
//  - raw s_barrier + BARE counted waitcnt asm (no memory clobbers) -> the
//    clean test of r1's clobber-drain theory (m201 template shape)
//  - counted vmcnt(4) once per K-tile (phases 4/8), never 0 mid-loop
// Stage slotting:
//   tile t ph1/ph2 -> stage (t+1).A0/A1 ; tile t ph3/ph4 -> stage (t+2).B0/B1
//   vmcnt(4) at tile end leaves exactly the 4 newest half-tile loads in
//   flight -> tile t+1 fully landed.
// ---------------------------------------------------------------------------
template <int BUF, int MH>
__device__ __forceinline__ void rdA(bf16x8 (&af)[4][2], const char* a0,
                                    const char* a1) {
#pragma unroll
  for (int i = 0; i < 4; ++i) {
    af[i][0] = *(const bf16x8*)(a0 + BUF * 32768 + MH * 8192 + i * 2048);
    af[i][1] = *(const bf16x8*)(a1 + BUF * 32768 + MH * 8192 + i * 2048);
  }
}

template <int BUF, int NH>
__device__ __forceinline__ void rdB(bf16x8 (&bfr)[2][2], const char* b0,
                                    const char* b1) {
#pragma unroll
  for (int j = 0; j < 2; ++j) {
    bfr[j][0] = *(const bf16x8*)(b0 + BUF * 32768 + NH * 4096 + j * 2048);
    bfr[j][1] = *(const bf16x8*)(b1 + BUF * 32768 + NH * 4096 + j * 2048);
  }
}

template <int MH, int NH>
__device__ __forceinline__ void mfma16x(f32x4 (&acc)[8][4], bf16x8 (&af)[4][2],
                                        bf16x8 (&bfr)[2][2]) {
  __builtin_amdgcn_s_setprio(1);
#pragma unroll
  for (int i = 0; i < 4; ++i)
#pragma unroll
    for (int j = 0; j < 2; ++j)
#pragma unroll
      for (int ks = 0; ks < 2; ++ks)
        acc[MH * 4 + i][NH * 2 + j] = __builtin_amdgcn_mfma_f32_16x16x32_bf16(
            af[i][ks], bfr[j][ks], acc[MH * 4 + i][NH * 2 + j], 0, 0, 0);
  __builtin_amdgcn_s_setprio(0);
}

__device__ __forceinline__ void gemm256_core(
    const bf16* __restrict__ A, const bf16* __restrict__ Bt, int K,
    int m0, int n0, bf16* As, bf16* Bs, f32x4 (&acc)[8][4]) {
  const int t = threadIdx.x;          // 0..511
  const int lane = t & 63;
  const int wave = t >> 6;            // 0..7
  const int wr = wave >> 2;           // 0..1 (M)
  const int wc = wave & 3;            // 0..3 (N)
  const int l15 = lane & 15;
  const int quad = lane >> 4;

  // Staging: chunk c = p*512+t covers 16B; row r = c>>3 (0..127 within half),
  // slot s = c&7 stores k-group g = s ^ (r&7) (pre-swizzled global source).
  const bf16* gA[2];
  const bf16* gB[2];
  int lOff[2];
#pragma unroll
  for (int p = 0; p < 2; ++p) {
    int c = p * 512 + t;
    int r = c >> 3;
    int g = (c & 7) ^ (r & 7);
    gA[p] = A + (size_t)(m0 + r) * K + g * 8;
    gB[p] = Bt + (size_t)(n0 + r) * K + g * 8;
    lOff[p] = c * 16;
  }
  const size_t rowH = (size_t)128 * K;  // elements: half-tile row step

  auto stA = [&](int tile, int h) {
#pragma unroll
    for (int p = 0; p < 2; ++p)
      async16(gA[p] + (size_t)h * rowH + tile * 64,
              (char*)As + (tile & 1) * 32768 + h * 16384 + lOff[p]);
  };
  auto stB = [&](int tile, int h) {
#pragma unroll
    for (int p = 0; p < 2; ++p)
      async16(gB[p] + (size_t)h * rowH + tile * 64,
              (char*)Bs + (tile & 1) * 32768 + h * 16384 + lOff[p]);
  };

  // Row-invariant swizzled read bases: byte = ra*128 + ((ks*4+quad)^(l15&7))*16
  // with ra&7 == l15&7 for every fragment row this lane touches.
  const int swz0 = ((0 * 4 + quad) ^ (l15 & 7)) * 16;  // bytes
  const int swz1 = ((1 * 4 + quad) ^ (l15 & 7)) * 16;
  const char* aP0 = (const char*)As + (wr * 128 + l15) * 128 + swz0;
  const char* aP1 = (const char*)As + (wr * 128 + l15) * 128 + swz1;
  const char* bP0 = (const char*)Bs + (wc * 64 + l15) * 128 + swz0;
  const char* bP1 = (const char*)Bs + (wc * 64 + l15) * 128 + swz1;

#pragma unroll
  for (int i = 0; i < 8; ++i)
#pragma unroll
    for (int j = 0; j < 4; ++j) acc[i][j] = (f32x4){0.f, 0.f, 0.f, 0.f};

  const int NT = K >> 6;   // K / 64 (even)
  const int NI = NT >> 1;

  // Prologue: tile0 {B0,B1,A0,A1} + tile1 {B0,B1}; wait tile0 (leave 4 loads).
  stB(0, 0); stB(0, 1); stA(0, 0); stA(0, 1);
  stB(1, 0); stB(1, 1);
  asm volatile("s_waitcnt vmcnt(4)");
  __builtin_amdgcn_s_barrier();

  bf16x8 aF[4][2], bF0[2][2], bF1[2][2];

  for (int it = 0; it < NI; ++it) {
    const int t0 = 2 * it;
    const bool more = (it + 1 < NI);

    // ---- tile t0 (buf 0) ----
    rdA<0, 0>(aF, aP0, aP1);                 // ph1: 12 ds_reads
    rdB<0, 0>(bF0, bP0, bP1);
    stA(t0 + 1, 0);
    __builtin_amdgcn_s_barrier();
    asm volatile("s_waitcnt lgkmcnt(0)");
    mfma16x<0, 0>(acc, aF, bF0);
    __builtin_amdgcn_s_barrier();

    rdB<0, 1>(bF1, bP0, bP1);                // ph2: 4 ds_reads
    stA(t0 + 1, 1);
    __builtin_amdgcn_s_barrier();
    asm volatile("s_waitcnt lgkmcnt(0)");
    mfma16x<0, 1>(acc, aF, bF1);
    __builtin_amdgcn_s_barrier();

    rdA<0, 1>(aF, aP0, aP1);                 // ph3: 8 ds_reads
    if (more) stB(t0 + 2, 0);
    __builtin_amdgcn_s_barrier();
    asm volatile("s_waitcnt lgkmcnt(0)");
    mfma16x<1, 0>(acc, aF, bF0);
    __builtin_amdgcn_s_barrier();

    if (more) stB(t0 + 2, 1);                // ph4
    __builtin_amdgcn_s_barrier();
    mfma16x<1, 1>(acc, aF, bF1);
    if (more) { asm volatile("s_waitcnt vmcnt(4)"); }
    else      { asm volatile("s_waitcnt vmcnt(0)"); }
    __builtin_amdgcn_s_barrier();

    // ---- tile t0+1 (buf 1) ----
    rdA<1, 0>(aF, aP0, aP1);                 // ph5
    rdB<1, 0>(bF0, bP0, bP1);
    if (more) stA(t0 + 2, 0);
    __builtin_amdgcn_s_barrier();
    asm volatile("s_waitcnt lgkmcnt(0)");
    mfma16x<0, 0>(acc, aF, bF0);
    __builtin_amdgcn_s_barrier();

    rdB<1, 1>(bF1, bP0, bP1);                // ph6
    if (more) stA(t0 + 2, 1);
    __builtin_amdgcn_s_barrier();
    asm volatile("s_waitcnt lgkmcnt(0)");
    mfma16x<0, 1>(acc, aF, bF1);
    __builtin_amdgcn_s_barrier();

    rdA<1, 1>(aF, aP0, aP1);                 // ph7
    if (more) stB(t0 + 3, 0);
    __builtin_amdgcn_s_barrier();
    asm volatile("s_waitcnt lgkmcnt(0)");
    mfma16x<1, 0>(acc, aF, bF0);
    __builtin_amdgcn_s_barrier();

    if (more) stB(t0 + 3, 1);                // ph8
    __builtin_amdgcn_s_barrier();
    mfma16x<1, 1>(acc, aF, bF1);
    if (more) { asm volatile("s_waitcnt vmcnt(4)"); }
    __builtin_amdgcn_s_barrier();
  }
}

template <int ACT>
__global__ __launch_bounds__(512, 2) void gemm256(
    const bf16* __restrict__ A, const bf16* __restrict__ Bt,
    const bf16* __restrict__ bias, bf16* __restrict__ C,
    int M, int N, int K, const int* __restrict__ gate) {
  if (gate && *gate == 0) return;
  __shared__ __align__(16) bf16 As[2 * 16384];
  __shared__ __align__(16) bf16 Bs[2 * 16384];
  int bx = blockIdx.x, by = blockIdx.y;
  xcd_swizzle(bx, by);
  const int m0 = by * 256;
  const int n0 = bx * 256;
  f32x4 acc[8][4];
  gemm256_core(A, Bt, K, m0, n0, As, Bs, acc);

  const int lane = threadIdx.x & 63;
  const int wave = threadIdx.x >> 6;
  const int wr = wave >> 2;
  const int wc = wave & 3;
  const int l15 = lane & 15;
  const int quad = lane >> 4;
  float bv[4];
#pragma unroll
  for (int j = 0; j < 4; ++j) bv[j] = bf2f(bias[n0 + wc * 64 + j * 16 + l15]);
  // j innermost: each row's 4x32B segments issue back-to-back (full sectors)
#pragma unroll
  for (int i = 0; i < 8; ++i) {
#pragma unroll
    for (int r = 0; r < 4; ++r) {
      int row = m0 + wr * 128 + i * 16 + quad * 4 + r;
#pragma unroll
      for (int j = 0; j < 4; ++j) {
        int col = n0 + wc * 64 + j * 16 + l15;
        float v = acc[i][j][r] + bv[j];
        if (ACT == 1) v = gelu_f(v);
        C[(size_t)row * N + col] = f2bf(v);
      }
    }
  }
  (void)M;
}

// sim variant: acc = q @ keys^T; epilogue scales by rsqrt(qsum)*kscale,
// packed-max reduce per row (hi=ordered float, lo=~idx) via u64 atomicMax.
__global__ __launch_bounds__(512, 2) void gemm256_sim(
    const bf16* __restrict__ Q, const bf16* __restrict__ Kb,
    const float* __restrict__ qsum, const float* __restrict__ kscale,
    unsigned long long* __restrict__ amax, int M, int N, int K,
    const int* __restrict__ gate) {
  if (*gate == 0) return;
  __shared__ __align__(16) bf16 As[2 * 16384];
  __shared__ __align__(16) bf16 Bs[2 * 16384];
  int bx = blockIdx.x, by = blockIdx.y;
  xcd_swizzle(bx, by);
  const int m0 = by * 256;
  const int n0 = bx * 256;
  f32x4 acc[8][4];
  gemm256_core(Q, Kb, K, m0, n0, As, Bs, acc);

  const int lane = threadIdx.x & 63;
  const int wave = threadIdx.x >> 6;
  const int wr = wave >> 2;
  const int wc = wave & 3;
  const int l15 = lane & 15;
  const int quad = lane >> 4;

  float ks4[4];
#pragma unroll
  for (int j = 0; j < 4; ++j) ks4[j] = kscale[n0 + wc * 64 + j * 16 + l15];

#pragma unroll
  for (int i = 0; i < 8; ++i) {
#pragma unroll
    for (int r = 0; r < 4; ++r) {
      int row = m0 + wr * 128 + i * 16 + quad * 4 + r;
      float qs = rsqrtf(fmaxf(qsum[row], 1e-16f));  // == 1/max(norm,1e-8)
      float best = -1e30f;
      int bidx = 0;
#pragma unroll
      for (int j = 0; j < 4; ++j) {
        int col = n0 + wc * 64 + j * 16 + l15;
        float v = acc[i][j][r] * qs * ks4[j];
        if (v > best) { best = v; bidx = col; }
      }
      unsigned int u = __float_as_uint(best);
      unsigned int ou = (u & 0x80000000u) ? ~u : (u | 0x80000000u);
      unsigned long long pk =
          ((unsigned long long)ou << 32) |
          (unsigned long long)(0xFFFFFFFFu - (unsigned int)bidx);
#pragma unroll
      for (int m = 1; m < 16; m <<= 1) {
        unsigned long long o = (unsigned long long)__shfl_xor((long long)pk, m, 64);
        if (o > pk) pk = o;
      }
      if (l15 == 0) atomicMax(amax + row, pk);
    }
  }
  (void)M;
}

// 64x64-tile conf-net GEMM. ZSUM: block (0,0) thread 0 zeroes the cmean
// accumulator (dispatch ordering puts this strictly before conf_head_reduce).
template <int ACT>
__global__ __launch_bounds__(256, 2) void gemm64(
    const bf16* __restrict__ A, const bf16* __restrict__ Bt,
    const bf16* __restrict__ bias, bf16* __restrict__ C,
    float* __restrict__ zsum, int M, int N, int K,
    const int* __restrict__ gate) {
  if (gate && *gate == 0) return;
  if (zsum && blockIdx.x == 0 && blockIdx.y == 0 && threadIdx.x == 0)
    *zsum = 0.f;
  __shared__ __align__(16) bf16 As[64 * 64];
  __shared__ __align__(16) bf16 Bs[64 * 64];

  const int t = threadIdx.x;
  const int lane = t & 63;
  const int wave = t >> 6;
  const int m0 = blockIdx.y * 64;
  const int n0 = blockIdx.x * 64;

  const bf16* gA[2];
  const bf16* gB[2];
  int lOff[2];
#pragma unroll
  for (int p = 0; p < 2; ++p) {
    int c = p * 256 + t;
    int r = c >> 3;
    int g = (c & 7) ^ (r & 7);
    gA[p] = A + (size_t)(m0 + r) * K + g * 8;
    gB[p] = Bt + (size_t)(n0 + r) * K + g * 8;
    lOff[p] = c * 16;
  }

  f32x4 acc[2][2];
#pragma unroll
  for (int i = 0; i < 2; ++i)
#pragma unroll
    for (int j = 0; j < 2; ++j) acc[i][j] = (f32x4){0.f, 0.f, 0.f, 0.f};

  const int wrow = (wave >> 1) * 32;
  const int wcol = (wave & 1) * 32;
  const int l15 = lane & 15;
  const int quad = lane >> 4;

  for (int kt = 0; kt < K; kt += 64) {
#pragma unroll
    for (int p = 0; p < 2; ++p) {
      async16(gA[p], (char*)As + lOff[p]);
      async16(gB[p], (char*)Bs + lOff[p]);
      gA[p] += 64;
      gB[p] += 64;
    }
    asm volatile("s_waitcnt vmcnt(0)" ::: "memory");
    __syncthreads();
#pragma unroll
    for (int ks = 0; ks < 2; ++ks) {
      bf16x8 af[2], bfv[2];
#pragma unroll
      for (int i = 0; i < 2; ++i) {
        int ra = wrow + i * 16 + l15;
        int g = ks * 4 + quad;
        af[i] = *(const bf16x8*)(As + ra * 64 + ((g ^ (ra & 7)) * 8));
        int rb = wcol + i * 16 + l15;
        bfv[i] = *(const bf16x8*)(Bs + rb * 64 + ((g ^ (rb & 7)) * 8));
      }
#pragma unroll
      for (int i = 0; i < 2; ++i)
#pragma unroll
        for (int j = 0; j < 2; ++j)
          acc[i][j] = __builtin_amdgcn_mfma_f32_16x16x32_bf16(af[i], bfv[j],
                                                              acc[i][j], 0, 0, 0);
    }
    __syncthreads();
  }

#pragma unroll
  for (int j = 0; j < 2; ++j) {
    int col = n0 + wcol + j * 16 + l15;
    float bv = bf2f(bias[col]);
#pragma unroll
    for (int i = 0; i < 2; ++i) {
#pragma unroll
      for (int r = 0; r < 4; ++r) {
        int row = m0 + wrow + i * 16 + quad * 4 + r;
        float v = acc[i][j][r] + bv;
        if (ACT == 1) v = gelu_f(v);
        C[(size_t)row * N + col] = f2bf(v);
      }
    }
  }
}

// --- small kernels ---------------------------------------------------------

__global__ void transpose_any(const void* __restrict__ src, bf16* __restrict__ dst,
                              int R, int C, const int* __restrict__ flag) {
  __shared__ bf16 tile[64][65];
  const int isf = *flag;
  int c0 = blockIdx.x * 64, r0 = blockIdx.y * 64;
#pragma unroll 4
  for (int p = 0; p < 16; ++p) {
    int idx = p * 256 + threadIdx.x;
    int r = idx >> 6, c = idx & 63;
    size_t si = (size_t)(r0 + r) * C + (c0 + c);
    tile[r][c] = isf ? f2bf(((const float*)src)[si]) : ((const bf16*)src)[si];
  }
  __syncthreads();
#pragma unroll 4
  for (int p = 0; p < 16; ++p) {
    int idx = p * 256 + threadIdx.x;
    int r = idx >> 6, c = idx & 63;
    dst[(size_t)(c0 + r) * R + (r0 + c)] = tile[c][r];
  }
}

__global__ void key_scale(const bf16* __restrict__ keys, const void* __restrict__ usage,
                          float* __restrict__ kscale, int cols,
                          const int* __restrict__ flag) {
  int row = blockIdx.x;
  const bf16* xr = keys + (size_t)row * cols;
  float s = 0.f;
  for (int i = threadIdx.x * 8; i < cols; i += 256 * 8) {
    union { uint4 u; bf16 h[8]; } u;
    u.u = *(const uint4*)(xr + i);
#pragma unroll
    for (int j = 0; j < 8; ++j) { float f = bf2f(u.h[j]); s += f * f; }
  }
  __shared__ float red[256];
  red[threadIdx.x] = s;
  __syncthreads();
  for (int k = 128; k > 0; k >>= 1) {
    if (threadIdx.x < k) red[threadIdx.x] += red[threadIdx.x + k];
    __syncthreads();
  }
  if (threadIdx.x == 0) {
    float us = *flag ? ((const float*)usage)[row] : bf2f(((const bf16*)usage)[row]);
    kscale[row] = us / fmaxf(sqrtf(red[0]), 1e-8f);
  }
}

// per-row conf head + per-block partial of sum(conf) -> one atomicAdd/block
__global__ void conf_head_reduce(const bf16* __restrict__ h2,
                                 const bf16* __restrict__ w3,
                                 const bf16* __restrict__ b3,
                                 const bf16* __restrict__ slope,
                                 const bf16* __restrict__ cbias,
                                 float* __restrict__ conf,
                                 float* __restrict__ csum,
                                 const int* __restrict__ gate) {
  if (gate && *gate == 0) return;
  int wave = threadIdx.x >> 6, lane = threadIdx.x & 63;
  int row = blockIdx.x * 4 + wave;
  const bf16* hr = h2 + (size_t)row * CH2_DIM;
  float s = bf2f(hr[lane]) * bf2f(w3[lane]) +
            bf2f(hr[lane + 64]) * bf2f(w3[lane + 64]);
  for (int m = 32; m > 0; m >>= 1) s += __shfl_xor(s, m, 64);
  __shared__ float part[4];
  if (lane == 0) {
    float raw = sigmoid_f(s + bf2f(b3[0]));
    float c = sigmoid_f(bf2f(slope[0]) * (raw - 0.5f) + bf2f(cbias[0]));
    conf[row] = c;
    part[wave] = c;
  }
  __syncthreads();
  if (threadIdx.x == 0)
    atomicAdd(csum, part[0] + part[1] + part[2] + part[3]);
}

// ctrl: [0]=adaptive_max_depth, [1]=depth, [2]=stopped, [3..7]=do_compute[d]
__global__ void init_control(const float* __restrict__ csum, int* __restrict__ ctrl) {
  float cf = 1.0f - (*csum / (float)B_DIM);
  int amd = 1 + (int)(cf * 4.0f);  // truncation matches .astype(int32)
  if (amd > 5) amd = 5;
  ctrl[0] = amd;
  ctrl[1] = 0;
  ctrl[2] = 0;
}

// control step + unconditional clear of lookup accumulators (grid B/256)
__global__ void step_control(const float* __restrict__ csum, int* __restrict__ ctrl,
                             int d, unsigned long long* __restrict__ amax,
                             float* __restrict__ qsum, int n) {
  int i = blockIdx.x * 256 + threadIdx.x;
  if (i < n) { amax[i] = 0ull; qsum[i] = 0.f; }
  if (i == 0) {
    int amd = ctrl[0], depth = ctrl[1], stopped = ctrl[2];
    bool brk = ((*csum / (float)B_DIM) >= 0.85f);
    bool active = (!stopped) && (d < amd);
    if (active) depth = d + 1;
    ctrl[3 + d] = (active && !brk) ? 1 : 0;
    if (active && brk) stopped = 1;
    ctrl[1] = depth;
    ctrl[2] = stopped;
  }
}

// in-place: replace S row with mem_values row only when best_sim > 0.9
__global__ void select_mem(const unsigned long long* __restrict__ amax,
                           const void* __restrict__ mv, bf16* __restrict__ S,
                           int Hc, const int* __restrict__ gate,
                           const int* __restrict__ flag) {
  if (*gate == 0) return;
  int b = blockIdx.x;
  unsigned long long pk = amax[b];
  unsigned int ou = (unsigned int)(pk >> 32);
  if (!(ou > 0xBF666666u)) return;  // ordered(0.9f); strict >
  int idx = (int)(0xFFFFFFFFu - (unsigned int)(pk & 0xFFFFFFFFull));
  bf16* dst = S + (size_t)b * Hc;
  if (*flag) {
    const float* src = (const float*)mv + (size_t)idx * Hc;
    for (int i = threadIdx.x; i < Hc; i += 256) dst[i] = f2bf(src[i]);
  } else {
    const uint4* src = (const uint4*)((const bf16*)mv + (size_t)idx * Hc);
    for (int i = threadIdx.x; i < Hc / 8; i += 256) ((uint4*)dst)[i] = src[i];
  }
}

__global__ void emit_state(const bf16* __restrict__ S, void* __restrict__ out,
                           int n, const int* __restrict__ flag) {
  int i = blockIdx.x * 256 + threadIdx.x;
  if (i >= n) return;
  if (*flag) ((float*)out)[i] = bf2f(S[i]);
  else       ((bf16*)out)[i] = S[i];
}

__global__ void write_tail(const float* __restrict__ conf, const int* __restrict__ ctrl,
                           void* __restrict__ out, int bh, int n,
                           const int* __restrict__ flag) {
  int i = blockIdx.x * 256 + threadIdx.x;
  if (i >= n) return;
  if (*flag) {
    ((float*)out)[bh + 1 + i] = conf[i];
    if (i == 0) ((float*)out)[bh] = (float)ctrl[1];
  } else {
    ((bf16*)out)[bh + 1 + i] = f2bf(conf[i]);
    if (i == 0) ((bf16*)out)[bh] = f2bf((float)ctrl[1]);
  }
}

// ---------------------------------------------------------------------------

extern "C" void kernel_launch(void* const* d_in, const int* in_sizes, int n_in,
                              void* d_out, int out_size, void* d_ws, size_t ws_size,
                              hipStream_t stream) {
  const int B = B_DIM, H = H_DIM, H2 = 2 * H_DIM, C1 = CH1_DIM, C2 = CH2_DIM,
            NM = NMEM_DIM;
  const void* x = d_in[0];
  const void* cw1 = d_in[1];
  const void* cb1 = d_in[2];
  const void* cw2 = d_in[3];
  const void* cb2 = d_in[4];
  const void* cw3 = d_in[5];
  const void* cb3 = d_in[6];
  const void* cal_slope = d_in[7];
  const void* cal_bias = d_in[8];
  const void* rw1 = d_in[9];
  const void* rb1 = d_in[10];
  const void* rw2 = d_in[11];
  const void* rb2 = d_in[12];
  const void* mqw = d_in[13];
  const void* mqb = d_in[14];
  const void* mem_keys = d_in[15];
  const void* mem_values = d_in[16];
  const void* mem_usage = d_in[17];

  char* ws = (char*)d_ws;
  size_t off = 0;
  auto alloc = [&](size_t bytes) -> char* {
    char* p = ws + off;
    off = (off + bytes + 255) & ~(size_t)255;
    return p;
  };
  bf16* rw1t = (bf16*)alloc((size_t)H2 * H * 2);
  bf16* rw2t = (bf16*)alloc((size_t)H * H2 * 2);
  bf16* mqwt = (bf16*)alloc((size_t)H * H * 2);
  bf16* cw1t = (bf16*)alloc((size_t)C1 * H * 2);
  bf16* cw2t = (bf16*)alloc((size_t)C2 * C1 * 2);
  bf16* keysb = (bf16*)alloc((size_t)NM * H * 2);
  bf16* S = (bf16*)alloc((size_t)B * H * 2);
  bf16* Hbuf = (bf16*)alloc((size_t)B * H2 * 2);  // q aliases lower half
  bf16* q = Hbuf;
  bf16* h1 = (bf16*)alloc((size_t)B * C1 * 2);
  bf16* h2 = (bf16*)alloc((size_t)B * C2 * 2);
  bf16* rb1b = (bf16*)alloc((size_t)H2 * 2);
  bf16* rb2b = (bf16*)alloc((size_t)H * 2);
  bf16* mqbb = (bf16*)alloc((size_t)H * 2);
  bf16* cb1b = (bf16*)alloc((size_t)C1 * 2);
  bf16* cb2b = (bf16*)alloc((size_t)C2 * 2);
  bf16* cw3b = (bf16*)alloc((size_t)C2 * 2);
  bf16* cb3b = (bf16*)alloc(256);
  bf16* slopeb = (bf16*)alloc(256);
  bf16* cbiasb = (bf16*)alloc(256);
  float* conf = (float*)alloc((size_t)B * 4);
  float* qsum = (float*)alloc((size_t)B * 4);
  float* kscale = (float*)alloc((size_t)NM * 4);
  unsigned long long* amax = (unsigned long long*)alloc((size_t)B * 8);
  float* csum = (float*)alloc(256);
  int* ctrl = (int*)alloc(256);
  int* dflag = (int*)alloc(256);
  (void)ws_size; (void)n_in; (void)in_sizes; (void)out_size;

  dim3 blk(256);
  dim3 blk512(512);

  // --- dtype probe ---
  flag_init<<<1, 1, 0, stream>>>(dflag);
  probe_dtype<<<64, blk, 0, stream>>>(x, dflag);

  // --- ingest to bf16 ---
  ingest<<<(B * H + 255) / 256, blk, 0, stream>>>(x, S, B * H, dflag);
  ingest<<<(NM * H + 255) / 256, blk, 0, stream>>>(mem_keys, keysb, NM * H, dflag);
  SmallJobs sj;
  sj.src[0] = rb1;       sj.dst[0] = rb1b;   sj.n[0] = H2;
  sj.src[1] = rb2;       sj.dst[1] = rb2b;   sj.n[1] = H;
  sj.src[2] = mqb;       sj.dst[2] = mqbb;   sj.n[2] = H;
  sj.src[3] = cb1;       sj.dst[3] = cb1b;   sj.n[3] = C1;
  sj.src[4] = cb2;       sj.dst[4] = cb2b;   sj.n[4] = C2;
  sj.src[5] = cw3;       sj.dst[5] = cw3b;   sj.n[5] = C2;
  sj.src[6] = cb3;       sj.dst[6] = cb3b;   sj.n[6] = 1;
  sj.src[7] = cal_slope; sj.dst[7] = slopeb; sj.n[7] = 1;
  sj.src[8] = cal_bias;  sj.dst[8] = cbiasb; sj.n[8] = 1;
  ingest_small<<<9, blk, 0, stream>>>(sj, dflag);

  // --- weight transposes (B^T form for GEMM) + key scales ---
  transpose_any<<<dim3(H2 / 64, H / 64), blk, 0, stream>>>(rw1, rw1t, H, H2, dflag);
  transpose_any<<<dim3(H / 64, H2 / 64), blk, 0, stream>>>(rw2, rw2t, H2, H, dflag);
  transpose_any<<<dim3(H / 64, H / 64), blk, 0, stream>>>(mqw, mqwt, H, H, dflag);
  transpose_any<<<dim3(C1 / 64, H / 64), blk, 0, stream>>>(cw1, cw1t, H, C1, dflag);
  transpose_any<<<dim3(C2 / 64, C1 / 64), blk, 0, stream>>>(cw2, cw2t, C1, C2, dflag);
  key_scale<<<NM, blk, 0, stream>>>(keysb, mem_usage, kscale, H, dflag);

  auto conf_pipe = [&](const bf16* Sin, const int* gate) {
    gemm64<1><<<dim3(C1 / 64, B / 64), blk, 0, stream>>>(Sin, cw1t, cb1b, h1,
                                                         csum, B, C1, H, gate);
    gemm64<1><<<dim3(C2 / 64, B / 64), blk, 0, stream>>>(h1, cw2t, cb2b, h2,
                                                         nullptr, B, C2, C1, gate);
    conf_head_reduce<<<B / 4, blk, 0, stream>>>(h2, cw3b, cb3b, slopeb, cbiasb,
                                                conf, csum, gate);
  };

  conf_pipe(S, nullptr);
  init_control<<<1, 1, 0, stream>>>(csum, ctrl);

  for (int d = 0; d < 5; ++d) {
    step_control<<<B / 256, blk, 0, stream>>>(csum, ctrl, d, amax, qsum, B);
    const int* gate = ctrl + 3 + d;
    if (d >= 1) {
      gemm_bt<128, 0, 1><<<dim3(H / 128, B / 128), blk, 0, stream>>>(
          S, mqwt, mqbb, q, qsum, B, H, H, gate);
      gemm256_sim<<<dim3(NM / 256, B / 256), blk512, 0, stream>>>(
          q, keysb, qsum, kscale, amax, B, NM, H, gate);
      select_mem<<<B, blk, 0, stream>>>(amax, mem_values, S, H, gate, dflag);
    }
    gemm256<1><<<dim3(H2 / 256, B / 256), blk512, 0, stream>>>(
        S, rw1t, rb1b, Hbuf, B, H2, H, gate);
    gemm_bt<128, 0, 0><<<dim3(H / 128, B / 128), blk, 0, stream>>>(
        Hbuf, rw2t, rb2b, S, nullptr, B, H, H2, gate);
    conf_pipe(S, gate);
  }

  emit_state<<<(B * H + 255) / 256, blk, 0, stream>>>(S, d_out, B * H, dflag);
  write_tail<<<B / 256, blk, 0, stream>>>(conf, ctrl, d_out, B * H, B, dflag);
}